// Round 18
// baseline (152.436 us; speedup 1.0000x reference)
//
#include <hip/hip_runtime.h>

#define BS 16
#define NH 16
#define LQ 4096
#define DH 32

constexpr size_t OUT_ELEMS = (size_t)BS * NH * LQ * DH;   // 33,554,432
constexpr int HDE = NH * DH * DH;           // 16384
constexpr int NSPLIT = 4;                   // block owns 1024 consecutive s
constexpr int NCH = 8;                      // 8 x 128-s windows per block

__device__ __forceinline__ void fma4(float4& a, float s, const float4& v) {
    a.x = fmaf(s, v.x, a.x);
    a.y = fmaf(s, v.y, a.y);
    a.z = fmaf(s, v.z, a.z);
    a.w = fmaf(s, v.w, a.w);
}

// ---------------- Kernel A: partial K@V (R17 machinery, streaming grid) ----------------
// Change vs R17: nsplit 32 -> 4. Each block walks 8 consecutive 128-s windows
// of ONE bh => its DRAM request stream is long + sequential (K row segments
// 4 KB, V 128 KB contiguous). Theory: the 95-104us plateau at <25% on every
// pipe is DRAM/L2 efficiency (~20%) on scattered 512B segments from ~500
// concurrent blocks; fetch-rate 1.4 TB/s invariant across all structures.
template<int NCHT>
__global__ __launch_bounds__(256, 2) void kv_partial(const float* __restrict__ k,
                                                     const float* __restrict__ v,
                                                     float* __restrict__ part) {
    __shared__ float lds[8192];             // K[32][128] swz | V[128][32] swz; reduce reuses
    const int tid = threadIdx.x;
    const int w   = tid >> 6;
    const int l   = tid & 63;
    const int nsplit = 32 / NCHT;
    const int p  = blockIdx.x % nsplit;
    const int bh = blockIdx.x / nsplit;

    const int tw = tid & 31;
    const int sp = tid >> 5;                // 0..7: 16-s slice
    const int dg = tw >> 3;                 // 0..3
    const int eg = tw & 7;                  // 0..7
    const int d0 = dg << 3;                 // 8 rows

    const float* kb = k + (size_t)bh * DH * LQ;
    const float* vb = v + (size_t)bh * LQ * DH;
    float* kt = lds;                        // 4096 floats
    float* vt = lds + 4096;                 // 4096 floats

    // staging constants
    const int kr   = tid >> 3;              // K row 0..31
    const int km   = tid & 7;               // chunk position
    const int kswz = (kr >> 2) & 7;
    const int vs   = tid >> 1;              // V row 0..127
    const int vh   = tid & 1;               // e-half
    const int vswz = vs & 7;

    float4 acc[8];
#pragma unroll
    for (int i = 0; i < 8; ++i) acc[i] = make_float4(0.f, 0.f, 0.f, 0.f);

#pragma unroll
    for (int c = 0; c < NCHT; ++c) {
        const int s0 = (p * NCHT + c) << 7; // window's 128-s base (consecutive!)
        if (c > 0) __syncthreads();         // WAR: prior window's reads done

        // ---- stage: 8 plain float4 loads (deep MLP), then swizzled ds_writes ----
        float4 kst[4], vst[4];
#pragma unroll
        for (int j = 0; j < 4; ++j)
            kst[j] = *(const float4*)(kb + (size_t)kr * LQ + s0 + ((km + 8 * j) << 2));
#pragma unroll
        for (int j = 0; j < 4; ++j)
            vst[j] = *(const float4*)(vb + ((size_t)(s0 + vs) << 5) + (vh << 4) + (j << 2));
#pragma unroll
        for (int j = 0; j < 4; ++j)
            *(float4*)(kt + (kr << 7) + (((km + 8 * j) ^ kswz) << 2)) = kst[j];
#pragma unroll
        for (int j = 0; j < 4; ++j) {
            const int g = (vh << 2) + j;    // e-chunk 0..7
            *(float4*)(vt + (vs << 5) + ((g ^ vswz) << 2)) = vst[j];
        }
        __syncthreads();                    // tiles resident

        // ---- compute: pure LDS + FMA ----
#pragma unroll
        for (int st = 0; st < 4; ++st) {
            const int cc = (sp << 2) + st;  // s-chunk 0..31 (4 s)
            float4 kq[8];
#pragma unroll
            for (int i = 0; i < 8; ++i) {
                const int r = d0 + i;
                kq[i] = *(const float4*)(kt + (r << 7) + ((cc ^ ((r >> 2) & 7)) << 2));
            }
#pragma unroll
            for (int u = 0; u < 4; ++u) {
                const int s = (cc << 2) + u;
                const float4 vu = *(const float4*)(vt + (s << 5) + ((eg ^ (s & 7)) << 2));
#pragma unroll
                for (int i = 0; i < 8; ++i) {
                    const float ks = (u == 0) ? kq[i].x
                                   : (u == 1) ? kq[i].y
                                   : (u == 2) ? kq[i].z : kq[i].w;
                    fma4(acc[i], ks, vu);
                }
            }
        }
    }

    // ---- reduce (R12-proven): butterfly over sp-halves, then 4 waves via LDS ----
#pragma unroll
    for (int i = 0; i < 8; ++i) {
        acc[i].x += __shfl_xor(acc[i].x, 32);
        acc[i].y += __shfl_xor(acc[i].y, 32);
        acc[i].z += __shfl_xor(acc[i].z, 32);
        acc[i].w += __shfl_xor(acc[i].w, 32);
    }

    __syncthreads();                        // all staging reads done: reuse lds
    if (l < 32) {
        float* dst = lds + w * 1152 + l * 36;
#pragma unroll
        for (int i = 0; i < 8; ++i) *(float4*)(dst + (i << 2)) = acc[i];
    }
    __syncthreads();

    const int fdg = (tid >> 6) & 3;
    const int fi  = (tid >> 3) & 7;
    const int feg = tid & 7;
    const int off = (fdg * 8 + feg) * 36 + (fi << 2);
    float4 r0 = *(const float4*)(lds + off);
    const float4 r1 = *(const float4*)(lds + 1152 + off);
    const float4 r2 = *(const float4*)(lds + 2304 + off);
    const float4 r3 = *(const float4*)(lds + 3456 + off);
    r0.x = (r0.x + r1.x) + (r2.x + r3.x);
    r0.y = (r0.y + r1.y) + (r2.y + r3.y);
    r0.z = (r0.z + r1.z) + (r2.z + r3.z);
    r0.w = (r0.w + r1.w) + (r2.w + r3.w);
    *(float4*)(part + ((size_t)p * (BS * NH) + bh) * 1024 + (tid << 2)) = r0;
}

// ---------------- DIAGNOSTIC: pure-stream probe of kv's exact load pattern ----
// 512 blocks (bh 0..127, half the data), kv's exact addresses, ZERO LDS /
// barriers / FMA-structure -- just loads + register accumulate + 1 store.
// Verdict: dur ~45us (1.4 TB/s) => memory-pattern-bound; ~13-20us (5 TB/s)
// => fill->barrier->compute structure-bound.
__global__ __launch_bounds__(256, 2) void stream_probe(const float* __restrict__ k,
                                                       const float* __restrict__ v,
                                                       float* __restrict__ scratch) {
    const int tid = threadIdx.x;
    const int p   = blockIdx.x & 3;
    const int bh  = blockIdx.x >> 2;        // 0..127
    const int kr  = tid >> 3;
    const int km  = tid & 7;
    const int vs  = tid >> 1;
    const int vh  = tid & 1;

    const float* kb = k + (size_t)bh * DH * LQ;
    const float* vb = v + (size_t)bh * LQ * DH;

    float4 a = make_float4(0.f, 0.f, 0.f, 0.f);
#pragma unroll 1
    for (int c = 0; c < NCH; ++c) {
        const int s0 = (p * NCH + c) << 7;
        float4 t;
#pragma unroll
        for (int j = 0; j < 4; ++j) {
            t = *(const float4*)(kb + (size_t)kr * LQ + s0 + ((km + 8 * j) << 2));
            a.x += t.x; a.y += t.y; a.z += t.z; a.w += t.w;
        }
#pragma unroll
        for (int j = 0; j < 4; ++j) {
            t = *(const float4*)(vb + ((size_t)(s0 + vs) << 5) + (vh << 4) + (j << 2));
            a.x += t.x; a.y += t.y; a.z += t.z; a.w += t.w;
        }
    }
    scratch[blockIdx.x * 256 + tid] = a.x + a.y + a.z + a.w;
}

// ---------------- Kernel B1: reduce partials over p ----------------
__global__ __launch_bounds__(256) void reduce_p(const float* __restrict__ part,
                                                float* __restrict__ wts, int nsp) {
    const int gidx = blockIdx.x * 256 + threadIdx.x;   // b*16384 + h*1024+d*32+e
    float s = 0.f;
#pragma unroll 4
    for (int pp = 0; pp < nsp; ++pp)
        s += part[((size_t)pp << 18) + gidx];
    wts[gidx] = s * (1.0f / 64.0f);                    // / sqrt(4096)
}

// ---------------- Kernel B2: softmax over batch axis (in-place on wts) ----------------
__global__ __launch_bounds__(256) void softmax_b(float* __restrict__ wts) {
    const int idx = blockIdx.x * 256 + threadIdx.x;    // 0..16383

    float sc[BS];
#pragma unroll
    for (int b = 0; b < BS; ++b) sc[b] = wts[((size_t)b << 14) + idx];
    float m = sc[0];
#pragma unroll
    for (int b = 1; b < BS; ++b) m = fmaxf(m, sc[b]);
    float sum = 0.f;
#pragma unroll
    for (int b = 0; b < BS; ++b) { sc[b] = __expf(sc[b] - m); sum += sc[b]; }
    const float inv = 1.0f / sum;
#pragma unroll
    for (int b = 0; b < BS; ++b) wts[((size_t)b << 14) + idx] = sc[b] * inv;
}

// ---------------- Kernel C: out = Q @ W ----------------
__global__ __launch_bounds__(256, 2) void qw(const float* __restrict__ q,
                                             const float* __restrict__ wts,
                                             float* __restrict__ out) {
    __shared__ float qs[128 * 36];
    const int blk = blockIdx.x;
    const int bh  = blk >> 5;
    const int lt  = blk & 31;
    const int tid = threadIdx.x;

    const float* qbase = q + ((size_t)bh * LQ + lt * 128) * DH;

#pragma unroll
    for (int pp = 0; pp < 4; ++pp) {
        const int idx = pp * 256 + tid;           // float4 index 0..1023
        const int row = idx >> 3;
        const int c4  = idx & 7;
        const float4 t = *(const float4*)(qbase + idx * 4);
        *(float4*)(qs + row * 36 + c4 * 4) = t;
    }

    const int lsub = tid >> 3;                    // 0..31
    const int e0   = (tid & 7) << 2;

    const int b = bh >> 4, h = bh & 15;
    float4 Wf[32];
    const float* wbase = wts + ((size_t)b << 14) + ((size_t)h << 10) + e0;
#pragma unroll
    for (int d = 0; d < 32; ++d) Wf[d] = *(const float4*)(wbase + d * DH);

    __syncthreads();

    float* obase = out + ((size_t)bh * LQ + lt * 128) * DH;

#pragma unroll
    for (int r = 0; r < 4; ++r) {
        const int lr = lsub + r * 32;
        const float* qrow = qs + lr * 36;
        float4 acc = {0, 0, 0, 0};
#pragma unroll
        for (int d4 = 0; d4 < 32; d4 += 4) {
            const float4 qv = *(const float4*)(qrow + d4);
            fma4(acc, qv.x, Wf[d4 + 0]);
            fma4(acc, qv.y, Wf[d4 + 1]);
            fma4(acc, qv.z, Wf[d4 + 2]);
            fma4(acc, qv.w, Wf[d4 + 3]);
        }
        *(float4*)(obase + (size_t)lr * DH + e0) = acc;
    }
}

extern "C" void kernel_launch(void* const* d_in, const int* in_sizes, int n_in,
                              void* d_out, int out_size, void* d_ws, size_t ws_size,
                              hipStream_t stream) {
    const float* q = (const float*)d_in[0];
    const float* k = (const float*)d_in[1];
    const float* v = (const float*)d_in[2];
    float* out  = (float*)d_out;
    float* wts  = out + OUT_ELEMS;          // attn_weights region of d_out
    float* part = (float*)d_ws;

    // partials: NSPLIT=4 -> 4 MB (ws proven >= 33.5 MB in R12-R17 runs)
    kv_partial<NCH><<<BS * NH * NSPLIT, 256, 0, stream>>>(k, v, part);
    reduce_p<<<(BS * HDE) / 256, 256, 0, stream>>>(part, wts, NSPLIT);
    softmax_b<<<HDE / 256, 256, 0, stream>>>(wts);
    qw<<<BS * NH * (LQ / 128), 256, 0, stream>>>(q, wts, out);

    // diagnostic probe LAST (scratch at 32 MB offset, outside partials)
    if (ws_size >= ((size_t)32 << 20) + 512 * 256 * 4)
        stream_probe<<<512, 256, 0, stream>>>(k, v, part + ((size_t)8 << 20));
}